// Round 1
// baseline (1039.254 us; speedup 1.0000x reference)
//
#include <hip/hip_runtime.h>

// LQR2: NS=32, NC=16, T=64, NB=512, NSC=48
// out: x[512][64][32] | u[512][64][16] | cost[512]
// ws:  K^T fp32 [512][64][32][16]  then k fp32 [512][64][16]  (~69 MB)

#define NSd 32
#define NCd 16
#define Td 64
#define NBd 512
#define NSCd 48

typedef __bf16 bf16x8 __attribute__((ext_vector_type(8)));
typedef __bf16 bf16x4 __attribute__((ext_vector_type(4)));
typedef float f32x4 __attribute__((ext_vector_type(4)));

#define MFMA16(a, b, c) __builtin_amdgcn_mfma_f32_16x16x32_bf16(a, b, c, 0, 0, 0)

#define XOFF ((size_t)0)
#define UOFF ((size_t)NBd * Td * NSd)                    // 1048576
#define COFF (UOFF + (size_t)NBd * Td * NCd)             // 1572864

__global__ __launch_bounds__(256, 2) void lqr_kernel(
    const float* __restrict__ x_init, const float* __restrict__ Qg,
    const float* __restrict__ pg, const float* __restrict__ Ag,
    const float* __restrict__ Bg, float* __restrict__ out,
    float* __restrict__ wsK, float* __restrict__ wskv) {
  const int b = blockIdx.x;
  const int tid = threadIdx.x;
  const int w = tid >> 6;
  const int lane = tid & 63;
  const int fn = lane & 15;     // MFMA: A row / B col / C col
  const int quad = lane >> 4;   // MFMA: k-chunk / C row group
  const int k0 = quad * 8;

  // ---------------- LDS ----------------
  __shared__ __attribute__((aligned(16))) float sQ[2][2304];   // Q tile dbuf (48x48)
  __shared__ float scx[Td][NSd];                               // rollout states
  __shared__ float sFf[NSd][NSCd];                             // F = [A|B] fp32
  __shared__ __attribute__((aligned(16))) __bf16 sFTh[NSCd][32], sFTl[NSCd][32]; // F^T hi/lo
  __shared__ __attribute__((aligned(16))) __bf16 sVh[NSd][32], sVl[NSd][32];     // V hi/lo (symmetric)
  __shared__ __attribute__((aligned(16))) __bf16 sWTh[NSCd][32], sWTl[NSCd][32]; // WT = F^T V
  __shared__ __attribute__((aligned(16))) __bf16 sXh[NSd][32], sXl[NSd][32];     // Qxu (k-padded w/ zeros)
  __shared__ __attribute__((aligned(16))) __bf16 sKTh[NSd][32], sKTl[NSd][32];   // Kt^T (k-padded)
  __shared__ float sQuu[16][17];
  __shared__ float sqt[NSCd];
  __shared__ float svv[NSd];
  __shared__ float skt[NCd];
  __shared__ __attribute__((aligned(16))) float sKT2[NSd][NCd]; // forward K^T
  __shared__ float skt2[NCd], sp[NSCd], sd[NSd], sxu[NSCd], sxn[NSd], sred[NSCd];
  __shared__ float ssx[NSd];
  __shared__ float scost;

  // ---------------- Phase A: setup ----------------
  for (int idx = tid; idx < 1536; idx += 256) {
    int i = idx / 48, j = idx - i * 48;
    sFf[i][j] = (j < 32) ? Ag[i * 32 + j] : Bg[i * 16 + (j - 32)];
  }
  for (int idx = tid; idx < 1536; idx += 256) {
    int a = idx >> 5, k = idx & 31;
    float f = (a < 32) ? Ag[k * 32 + a] : Bg[k * 16 + (a - 32)];
    __bf16 h = (__bf16)f;
    sFTh[a][k] = h;
    sFTl[a][k] = (__bf16)(f - (float)h);
  }
  for (int idx = tid; idx < 1024; idx += 256) {
    int r = idx >> 5, c = idx & 31;
    __bf16 z = (__bf16)0.f;
    sVh[r][c] = z; sVl[r][c] = z;
    sXh[r][c] = z; sXl[r][c] = z;
    sKTh[r][c] = z; sKTl[r][c] = z;
  }
  if (tid < 32) {
    float xi = x_init[b * 32 + tid];
    scx[0][tid] = xi;
    ssx[tid] = xi;
    svv[tid] = 0.f;
  }
  if (tid == 0) scost = 0.f;
  {
    const float4* src = (const float4*)(Qg + ((size_t)b * Td + 63) * 2304);
    float4* dst = (float4*)sQ[0];
    dst[tid] = src[tid];
    dst[tid + 256] = src[tid + 256];
    if (tid < 64) dst[tid + 512] = src[tid + 512];
  }
  __syncthreads();
  // cx rollout: cx[t+1] = A @ cx[t]
  for (int t = 0; t < Td - 1; ++t) {
    if (tid < 32) {
      float acc = 0.f;
#pragma unroll
      for (int j = 0; j < 32; ++j) acc += sFf[tid][j] * scx[t][j];
      scx[t + 1][tid] = acc;
    }
    __syncthreads();
  }

  // ---------------- Backward Riccati ----------------
  for (int t = Td - 1; t >= 0; --t) {
    const int cur = (Td - 1 - t) & 1, nxt = cur ^ 1;
    float4 pf0, pf1, pf2;
    if (t > 0) {  // prefetch Q[b,t-1] into regs
      const float4* src = (const float4*)(Qg + ((size_t)b * Td + (t - 1)) * 2304);
      pf0 = src[tid];
      pf1 = src[tid + 256];
      if (tid < 64) pf2 = src[tid + 512];
    }
    // P0: waves 0-2: WT = F^T @ V (uses V symmetry for B-frags). wave 3: qt vector.
    if (w < 3) {
      const int I = w;
      bf16x8 aH = *(const bf16x8*)&sFTh[16 * I + fn][k0];
      bf16x8 aL = *(const bf16x8*)&sFTl[16 * I + fn][k0];
#pragma unroll
      for (int J = 0; J < 2; ++J) {
        bf16x8 bH = *(const bf16x8*)&sVh[16 * J + fn][k0];
        bf16x8 bL = *(const bf16x8*)&sVl[16 * J + fn][k0];
        f32x4 acc = {0.f, 0.f, 0.f, 0.f};
        acc = MFMA16(aL, bH, acc);
        acc = MFMA16(aH, bL, acc);
        acc = MFMA16(aH, bH, acc);
#pragma unroll
        for (int r = 0; r < 4; ++r) {
          float v = acc[r];
          __bf16 h = (__bf16)v;
          sWTh[16 * I + 4 * quad + r][16 * J + fn] = h;
          sWTl[16 * I + 4 * quad + r][16 * J + fn] = (__bf16)(v - (float)h);
        }
      }
    } else if (lane < 48) {
      // qt[i] = p[b,t,i] + sum_k Q[k][i]*cx[t][k] (Q symmetric) + sum_k v[k]*F[k][i]
      float acc = pg[((size_t)b * Td + t) * 48 + lane];
#pragma unroll
      for (int k = 0; k < 32; ++k) acc += sQ[cur][k * 48 + lane] * scx[t][k];
#pragma unroll
      for (int k = 0; k < 32; ++k) acc += svv[k] * sFf[k][lane];
      sqt[lane] = acc;
    }
    __syncthreads();  // B1

    // P1: Qt = Qbt + WT @ F.  Qxx tiles stay in regs; Qxu -> sX (bf16); Quu -> fp32.
    f32x4 accQ = {0.f, 0.f, 0.f, 0.f};
    if (w < 3) {
      const int I = (w == 1) ? 1 : 0, J = (w == 0) ? 0 : 1;
      bf16x8 aH = *(const bf16x8*)&sWTh[16 * I + fn][k0];
      bf16x8 aL = *(const bf16x8*)&sWTl[16 * I + fn][k0];
      bf16x8 bH = *(const bf16x8*)&sFTh[16 * J + fn][k0];
      bf16x8 bL = *(const bf16x8*)&sFTl[16 * J + fn][k0];
#pragma unroll
      for (int r = 0; r < 4; ++r) accQ[r] = sQ[cur][(16 * I + 4 * quad + r) * 48 + 16 * J + fn];
      accQ = MFMA16(aL, bH, accQ);
      accQ = MFMA16(aH, bL, accQ);
      accQ = MFMA16(aH, bH, accQ);
    } else {
      bf16x8 bH = *(const bf16x8*)&sFTh[32 + fn][k0];
      bf16x8 bL = *(const bf16x8*)&sFTl[32 + fn][k0];
#pragma unroll
      for (int I2 = 0; I2 < 3; ++I2) {
        bf16x8 aH = *(const bf16x8*)&sWTh[16 * I2 + fn][k0];
        bf16x8 aL = *(const bf16x8*)&sWTl[16 * I2 + fn][k0];
        f32x4 acc;
#pragma unroll
        for (int r = 0; r < 4; ++r) acc[r] = sQ[cur][(16 * I2 + 4 * quad + r) * 48 + 32 + fn];
        acc = MFMA16(aL, bH, acc);
        acc = MFMA16(aH, bL, acc);
        acc = MFMA16(aH, bH, acc);
        if (I2 < 2) {
#pragma unroll
          for (int r = 0; r < 4; ++r) {
            float v = acc[r];
            __bf16 h = (__bf16)v;
            sXh[16 * I2 + 4 * quad + r][fn] = h;
            sXl[16 * I2 + 4 * quad + r][fn] = (__bf16)(v - (float)h);
          }
        } else {
#pragma unroll
          for (int r = 0; r < 4; ++r) sQuu[4 * quad + r][fn] = acc[r];
        }
      }
    }
    __syncthreads();  // B2

    // P2: solve Quu * X = [Qux | qu]  (Qux = Qxu^T via symmetry; RHS cols in regs)
    float rhs[16];
    if (tid < 32) {
#pragma unroll
      for (int i = 0; i < 16; ++i) rhs[i] = (float)sXh[tid][i] + (float)sXl[tid][i];
    } else if (tid == 32) {
#pragma unroll
      for (int i = 0; i < 16; ++i) rhs[i] = sqt[32 + i];
    }
#pragma unroll
    for (int r = 0; r < 15; ++r) {
      float pr = 1.0f / sQuu[r][r];
      if (tid <= 32) {
        float rr = rhs[r];
#pragma unroll
        for (int i = r + 1; i < 16; ++i) rhs[i] -= (sQuu[i][r] * pr) * rr;
      } else if (tid >= 64) {
        for (int idx = tid - 64; idx < 225; idx += 192) {
          int ii = 1 + idx / 15, cc = 1 + idx % 15;
          if (ii > r && cc > r) sQuu[ii][cc] -= (sQuu[ii][r] * pr) * sQuu[r][cc];
        }
      }
      __syncthreads();  // per-pivot barrier
    }
    if (tid <= 32) {  // back-substitution, barrier-free
      float xx[16];
#pragma unroll
      for (int r = 15; r >= 0; --r) {
        float s = rhs[r];
#pragma unroll
        for (int c = r + 1; c < 16; ++c) s -= sQuu[r][c] * xx[c];
        xx[r] = s / sQuu[r][r];
      }
      if (tid < 32) {  // Kt[u][j] = -xx[u]; store Kt^T bf16 + fp32 to ws
#pragma unroll
        for (int u = 0; u < 16; ++u) {
          float kv = -xx[u];
          __bf16 h = (__bf16)kv;
          sKTh[tid][u] = h;
          sKTl[tid][u] = (__bf16)(kv - (float)h);
        }
        float4* dst = (float4*)(wsK + (((size_t)b * Td + t) * 32 + tid) * 16);
        float4 v0 = {-xx[0], -xx[1], -xx[2], -xx[3]};
        float4 v1 = {-xx[4], -xx[5], -xx[6], -xx[7]};
        float4 v2 = {-xx[8], -xx[9], -xx[10], -xx[11]};
        float4 v3 = {-xx[12], -xx[13], -xx[14], -xx[15]};
        dst[0] = v0; dst[1] = v1; dst[2] = v2; dst[3] = v3;
      } else {  // tid == 32: kt
#pragma unroll
        for (int u = 0; u < 16; ++u) skt[u] = -xx[u];
        float4* dst = (float4*)(wskv + ((size_t)b * Td + t) * 16);
        float4 v0 = {-xx[0], -xx[1], -xx[2], -xx[3]};
        float4 v1 = {-xx[4], -xx[5], -xx[6], -xx[7]};
        float4 v2 = {-xx[8], -xx[9], -xx[10], -xx[11]};
        float4 v3 = {-xx[12], -xx[13], -xx[14], -xx[15]};
        dst[0] = v0; dst[1] = v1; dst[2] = v2; dst[3] = v3;
      }
    }
    __syncthreads();  // B18: sKT/skt ready

    // P4: Vn = Qxx + Qxu @ Kt (waves 0-2, accQ continues); wave3: vn; all: commit prefetch
    if (w < 3) {
      const int I = (w == 1) ? 1 : 0, J = (w == 0) ? 0 : 1;
      bf16x8 aH = *(const bf16x8*)&sXh[16 * I + fn][k0];
      bf16x8 aL = *(const bf16x8*)&sXl[16 * I + fn][k0];
      bf16x8 bH = *(const bf16x8*)&sKTh[16 * J + fn][k0];
      bf16x8 bL = *(const bf16x8*)&sKTl[16 * J + fn][k0];
      accQ = MFMA16(aL, bH, accQ);
      accQ = MFMA16(aH, bL, accQ);
      accQ = MFMA16(aH, bH, accQ);
#pragma unroll
      for (int r = 0; r < 4; ++r) {
        float v = accQ[r];
        __bf16 h = (__bf16)v;
        sVh[16 * I + 4 * quad + r][16 * J + fn] = h;
        sVl[16 * I + 4 * quad + r][16 * J + fn] = (__bf16)(v - (float)h);
      }
      if (w == 2) {  // mirror tile (0,1) -> (1,0) via symmetry, packed b64 writes
        bf16x4 th, tl;
#pragma unroll
        for (int r = 0; r < 4; ++r) {
          float v = accQ[r];
          __bf16 h = (__bf16)v;
          th[r] = h;
          tl[r] = (__bf16)(v - (float)h);
        }
        *(bf16x4*)&sVh[16 + fn][4 * quad] = th;
        *(bf16x4*)&sVl[16 + fn][4 * quad] = tl;
      }
    } else if (lane < 32) {  // vn = qx + Qxu @ kt
      float acc = sqt[lane];
#pragma unroll
      for (int u = 0; u < 16; ++u)
        acc += ((float)sXh[lane][u] + (float)sXl[lane][u]) * skt[u];
      svv[lane] = acc;
    }
    if (t > 0) {
      float4* dst = (float4*)sQ[nxt];
      dst[tid] = pf0;
      dst[tid + 256] = pf1;
      if (tid < 64) dst[tid + 512] = pf2;
    }
    __syncthreads();  // B19 (end of step)
  }

  // ---------------- Forward rollout ----------------
  // Q[b,0] is still resident in sQ[1] (backward t=0 used buffer 1).
  for (int t = 0; t < Td; ++t) {
    const int cur = (t + 1) & 1, nxt = cur ^ 1;
    float4 pf0, pf1, pf2;
    if (t < Td - 1) {
      const float4* src = (const float4*)(Qg + ((size_t)b * Td + (t + 1)) * 2304);
      pf0 = src[tid];
      pf1 = src[tid + 256];
      if (tid < 64) pf2 = src[tid + 512];
    }
    // P0: stage K^T, k, p; d = x - cx[t]; xu[0:32] = x
    {
      const size_t kb = ((size_t)b * Td + t) << 9;  // *512
      if (tid < 128) {
        float4 v = ((const float4*)(wsK + kb))[tid];
        *(float4*)&sKT2[tid >> 2][(tid & 3) * 4] = v;
      } else if (tid < 144) {
        skt2[tid - 128] = wskv[((size_t)b * Td + t) * 16 + (tid - 128)];
      } else if (tid < 192) {
        sp[tid - 144] = pg[((size_t)b * Td + t) * 48 + (tid - 144)];
      } else if (tid < 224) {
        sd[tid - 192] = ssx[tid - 192] - scx[t][tid - 192];
      } else {
        sxu[tid - 224] = ssx[tid - 224];
      }
    }
    __syncthreads();
    // P1: u = k + K(x - cx); emit x, u
    if (tid < 16) {
      float acc = skt2[tid];
#pragma unroll
      for (int j = 0; j < 32; ++j) acc += sKT2[j][tid] * sd[j];
      sxu[32 + tid] = acc;
      out[UOFF + ((size_t)b * Td + t) * 16 + tid] = acc;
    } else if (tid < 48) {
      out[XOFF + ((size_t)b * Td + t) * 32 + (tid - 16)] = ssx[tid - 16];
    }
    __syncthreads();
    // P2: cost terms y = Q @ xu (symmetric column reads); xn = F @ xu
    if (tid < 48) {
      float y = 0.f;
#pragma unroll
      for (int j = 0; j < 48; ++j) y += sQ[cur][j * 48 + tid] * sxu[j];
      sred[tid] = sxu[tid] * (0.5f * y + sp[tid]);
    } else if (tid >= 64 && tid < 96) {
      int i = tid - 64;
      float acc = 0.f;
#pragma unroll
      for (int j = 0; j < 48; ++j) acc += sFf[i][j] * sxu[j];
      sxn[i] = acc;
    }
    __syncthreads();
    // P3: accumulate cost; advance state; commit prefetched tile
    if (tid == 0) {
      float c = 0.f;
#pragma unroll
      for (int i = 0; i < 48; ++i) c += sred[i];
      scost += c;
    }
    if (tid < 32) ssx[tid] = sxn[tid];
    if (t < Td - 1) {
      float4* dst = (float4*)sQ[nxt];
      dst[tid] = pf0;
      dst[tid + 256] = pf1;
      if (tid < 64) dst[tid + 512] = pf2;
    }
    __syncthreads();
  }
  if (tid == 0) out[COFF + b] = scost;
}

extern "C" void kernel_launch(void* const* d_in, const int* in_sizes, int n_in,
                              void* d_out, int out_size, void* d_ws, size_t ws_size,
                              hipStream_t stream) {
  const float* x_init = (const float*)d_in[0];
  const float* Qg = (const float*)d_in[1];
  const float* pg = (const float*)d_in[2];
  const float* Ag = (const float*)d_in[3];
  const float* Bg = (const float*)d_in[4];
  float* out = (float*)d_out;
  float* wsK = (float*)d_ws;                       // 512*64*32*16 floats
  float* wskv = wsK + (size_t)NBd * Td * NSd * NCd;  // + 512*64*16 floats
  lqr_kernel<<<NBd, 256, 0, stream>>>(x_init, Qg, pg, Ag, Bg, out, wsK, wskv);
}

// Round 2
// 940.805 us; speedup vs baseline: 1.1046x; 1.1046x over previous
//
#include <hip/hip_runtime.h>

// LQR2: NS=32, NC=16, T=64, NB=512, NSC=48
// out: x[512][64][32] | u[512][64][16] | cost[512]
// ws:  K^T fp32 [512][64][32][16]  then k fp32 [512][64][16]  (~69 MB)
//
// R2: barrier diet. Backward: 3 barriers/step (was 19) — the 16x16 SPD solve
// is now wave-synchronous via __shfl (all 4 waves solve redundantly, RHS
// columns in lanes, pivot rows broadcast cross-lane; zero LDS, zero barriers).
// Forward: 2 barriers/step. cx rollout: wave-0 synchronous, no barriers.

#define NSd 32
#define NCd 16
#define Td 64
#define NBd 512
#define NSCd 48

typedef __bf16 bf16x8 __attribute__((ext_vector_type(8)));
typedef __bf16 bf16x4 __attribute__((ext_vector_type(4)));
typedef float f32x4 __attribute__((ext_vector_type(4)));

#define MFMA16(a, b, c) __builtin_amdgcn_mfma_f32_16x16x32_bf16(a, b, c, 0, 0, 0)

#define XOFF ((size_t)0)
#define UOFF ((size_t)NBd * Td * NSd)
#define COFF (UOFF + (size_t)NBd * Td * NCd)

__global__ __launch_bounds__(256, 2) void lqr_kernel(
    const float* __restrict__ x_init, const float* __restrict__ Qg,
    const float* __restrict__ pg, const float* __restrict__ Ag,
    const float* __restrict__ Bg, float* __restrict__ out,
    float* __restrict__ wsK, float* __restrict__ wskv) {
  const int b = blockIdx.x;
  const int tid = threadIdx.x;
  const int w = tid >> 6;
  const int lane = tid & 63;
  const int fn = lane & 15;
  const int quad = lane >> 4;
  const int k0 = quad * 8;

  // ---------------- LDS (single-buffered Q; ~54.6 KB total) ----------------
  __shared__ __attribute__((aligned(16))) float sQ[2304];
  __shared__ float scx[Td][NSd];
  __shared__ float sFf[NSd][NSCd];
  __shared__ __attribute__((aligned(16))) __bf16 sFTh[NSCd][32], sFTl[NSCd][32];
  __shared__ __attribute__((aligned(16))) __bf16 sVh[NSd][32], sVl[NSd][32];
  __shared__ __attribute__((aligned(16))) __bf16 sWTh[NSCd][32], sWTl[NSCd][32];
  __shared__ __attribute__((aligned(16))) __bf16 sXh[NSd][32], sXl[NSd][32];
  __shared__ __attribute__((aligned(16))) __bf16 sKTh[NSd][32], sKTl[NSd][32];
  __shared__ float sQuu[16][17];
  __shared__ float sqt[NSCd];
  __shared__ float svv[NSd];
  __shared__ __attribute__((aligned(16))) float sKT2[2][NSd][NCd];
  __shared__ float skt2[2][NCd], spf[2][NSCd];
  __shared__ float sxu[NSCd], sred[NSCd], ssx[NSd];

  // ---------------- setup ----------------
  for (int idx = tid; idx < 1536; idx += 256) {
    int i = idx / 48, j = idx - i * 48;
    sFf[i][j] = (j < 32) ? Ag[i * 32 + j] : Bg[i * 16 + (j - 32)];
  }
  for (int idx = tid; idx < 1536; idx += 256) {
    int a = idx >> 5, k = idx & 31;
    float f = (a < 32) ? Ag[k * 32 + a] : Bg[k * 16 + (a - 32)];
    __bf16 h = (__bf16)f;
    sFTh[a][k] = h;
    sFTl[a][k] = (__bf16)(f - (float)h);
  }
  for (int idx = tid; idx < 1024; idx += 256) {
    int r = idx >> 5, c = idx & 31;
    __bf16 z = (__bf16)0.f;
    sVh[r][c] = z; sVl[r][c] = z;
    sXh[r][c] = z; sXl[r][c] = z;
    sKTh[r][c] = z; sKTl[r][c] = z;
  }
  if (tid < 32) {
    float xi = x_init[b * 32 + tid];
    scx[0][tid] = xi;
    ssx[tid] = xi;
    svv[tid] = 0.f;
  }
  {  // stage Q[b,63]
    const float4* src = (const float4*)(Qg + ((size_t)b * Td + 63) * 2304);
    float4* dst = (float4*)sQ;
    dst[tid] = src[tid];
    dst[tid + 256] = src[tid + 256];
    if (tid < 64) dst[tid + 512] = src[tid + 512];
  }
  float ppf = 0.f;  // backward p[t] prefetch (w3 lanes<48)
  if (w == 3 && lane < 48) ppf = pg[((size_t)b * Td + 63) * 48 + lane];
  __syncthreads();

  // cx rollout, wave-0 synchronous (in-wave LDS ordering, no barriers)
  if (w == 0) {
    for (int t2 = 0; t2 < Td - 1; ++t2) {
      if (lane < 32) {
        float acc = 0.f;
#pragma unroll
        for (int j = 0; j < 32; j += 4) {
          float4 a4 = *(const float4*)&sFf[lane][j];
          acc += a4.x * scx[t2][j] + a4.y * scx[t2][j + 1] +
                 a4.z * scx[t2][j + 2] + a4.w * scx[t2][j + 3];
        }
        scx[t2 + 1][lane] = acc;
      }
    }
  }
  __syncthreads();

  // ---------------- backward Riccati: 3 barriers/step ----------------
  for (int t = Td - 1; t >= 0; --t) {
    float4 pf0, pf1, pf2;
    float ppfn;
    if (t > 0) {  // prefetch Q[t-1], p[t-1] into regs
      const float4* src = (const float4*)(Qg + ((size_t)b * Td + (t - 1)) * 2304);
      pf0 = src[tid];
      pf1 = src[tid + 256];
      if (tid < 64) pf2 = src[tid + 512];
      if (w == 3 && lane < 48) ppfn = pg[((size_t)b * Td + t - 1) * 48 + lane];
    }
    // P0: w0-2: WT = F^T V (V symmetric). w3: qt vector.
    if (w < 3) {
      const int I = w;
      bf16x8 aH = *(const bf16x8*)&sFTh[16 * I + fn][k0];
      bf16x8 aL = *(const bf16x8*)&sFTl[16 * I + fn][k0];
#pragma unroll
      for (int J = 0; J < 2; ++J) {
        bf16x8 bH = *(const bf16x8*)&sVh[16 * J + fn][k0];
        bf16x8 bL = *(const bf16x8*)&sVl[16 * J + fn][k0];
        f32x4 acc = {0.f, 0.f, 0.f, 0.f};
        acc = MFMA16(aL, bH, acc);
        acc = MFMA16(aH, bL, acc);
        acc = MFMA16(aH, bH, acc);
#pragma unroll
        for (int r = 0; r < 4; ++r) {
          float v = acc[r];
          __bf16 h = (__bf16)v;
          sWTh[16 * I + 4 * quad + r][16 * J + fn] = h;
          sWTl[16 * I + 4 * quad + r][16 * J + fn] = (__bf16)(v - (float)h);
        }
      }
    } else if (lane < 48) {
      float acc = ppf;  // p[b,t,lane]
#pragma unroll
      for (int k = 0; k < 32; ++k) acc += sQ[k * 48 + lane] * scx[t][k];
#pragma unroll
      for (int k = 0; k < 32; ++k) acc += svv[k] * sFf[k][lane];
      sqt[lane] = acc;
    }
    if (t > 0 && w == 3) ppf = ppfn;
    __syncthreads();  // B1

    // P1: Qt = Q + WT@F, 6 unique tiles over 4 waves.
    //  w0: Qxx(0,0)->accQ, Qxu(0,2)->sX rows 0-15
    //  w1: Qxx(1,1)->accQ, Qxu(1,2)->sX rows 16-31
    //  w2: Qxx(0,1)->accQ    w3: Quu(2,2)->sQuu
    f32x4 accQ = {0.f, 0.f, 0.f, 0.f};
    if (w < 2) {
      const int I = w;
      bf16x8 aH = *(const bf16x8*)&sWTh[16 * I + fn][k0];
      bf16x8 aL = *(const bf16x8*)&sWTl[16 * I + fn][k0];
      {
        bf16x8 bH = *(const bf16x8*)&sFTh[16 * I + fn][k0];
        bf16x8 bL = *(const bf16x8*)&sFTl[16 * I + fn][k0];
#pragma unroll
        for (int r = 0; r < 4; ++r)
          accQ[r] = sQ[(16 * I + 4 * quad + r) * 48 + 16 * I + fn];
        accQ = MFMA16(aL, bH, accQ);
        accQ = MFMA16(aH, bL, accQ);
        accQ = MFMA16(aH, bH, accQ);
      }
      {
        bf16x8 bH = *(const bf16x8*)&sFTh[32 + fn][k0];
        bf16x8 bL = *(const bf16x8*)&sFTl[32 + fn][k0];
        f32x4 acc;
#pragma unroll
        for (int r = 0; r < 4; ++r)
          acc[r] = sQ[(16 * I + 4 * quad + r) * 48 + 32 + fn];
        acc = MFMA16(aL, bH, acc);
        acc = MFMA16(aH, bL, acc);
        acc = MFMA16(aH, bH, acc);
#pragma unroll
        for (int r = 0; r < 4; ++r) {
          float v = acc[r];
          __bf16 h = (__bf16)v;
          sXh[16 * I + 4 * quad + r][fn] = h;
          sXl[16 * I + 4 * quad + r][fn] = (__bf16)(v - (float)h);
        }
      }
    } else if (w == 2) {
      bf16x8 aH = *(const bf16x8*)&sWTh[fn][k0];
      bf16x8 aL = *(const bf16x8*)&sWTl[fn][k0];
      bf16x8 bH = *(const bf16x8*)&sFTh[16 + fn][k0];
      bf16x8 bL = *(const bf16x8*)&sFTl[16 + fn][k0];
#pragma unroll
      for (int r = 0; r < 4; ++r)
        accQ[r] = sQ[(4 * quad + r) * 48 + 16 + fn];
      accQ = MFMA16(aL, bH, accQ);
      accQ = MFMA16(aH, bL, accQ);
      accQ = MFMA16(aH, bH, accQ);
    } else {
      bf16x8 aH = *(const bf16x8*)&sWTh[32 + fn][k0];
      bf16x8 aL = *(const bf16x8*)&sWTl[32 + fn][k0];
      bf16x8 bH = *(const bf16x8*)&sFTh[32 + fn][k0];
      bf16x8 bL = *(const bf16x8*)&sFTl[32 + fn][k0];
      f32x4 acc;
#pragma unroll
      for (int r = 0; r < 4; ++r)
        acc[r] = sQ[(32 + 4 * quad + r) * 48 + 32 + fn];
      acc = MFMA16(aL, bH, acc);
      acc = MFMA16(aH, bL, acc);
      acc = MFMA16(aH, bH, acc);
#pragma unroll
      for (int r = 0; r < 4; ++r) sQuu[4 * quad + r][fn] = acc[r];
    }
    __syncthreads();  // B2

    // commit Q prefetch (all sQ reads for this step are done)
    if (t > 0) {
      float4* dst = (float4*)sQ;
      dst[tid] = pf0;
      dst[tid + 256] = pf1;
      if (tid < 64) dst[tid + 512] = pf2;
    }

    // P2: wave-synchronous solve Quu * X = [Qux | qu] (redundant in each wave).
    // lane<32: column of Qux (= row of Qxu by symmetry); lane>=32: qu.
    float rhs[16];
    if (lane < 32) {
      bf16x8 xh0 = *(const bf16x8*)&sXh[lane][0];
      bf16x8 xh1 = *(const bf16x8*)&sXh[lane][8];
      bf16x8 xl0 = *(const bf16x8*)&sXl[lane][0];
      bf16x8 xl1 = *(const bf16x8*)&sXl[lane][8];
#pragma unroll
      for (int i = 0; i < 8; ++i) {
        rhs[i] = (float)xh0[i] + (float)xl0[i];
        rhs[8 + i] = (float)xh1[i] + (float)xl1[i];
      }
    } else {
#pragma unroll
      for (int i = 0; i < 16; ++i) rhs[i] = sqt[32 + i];
    }
    float quu[16];
#pragma unroll
    for (int i = 0; i < 16; ++i) quu[i] = sQuu[i][fn];
#pragma unroll
    for (int r = 0; r < 15; ++r) {
      float inv = __builtin_amdgcn_rcpf(__shfl(quu[r], r));
      float rr = rhs[r], qr = quu[r];
#pragma unroll
      for (int i = r + 1; i < 16; ++i) {
        float m = __shfl(quu[i], r) * inv;
        rhs[i] -= m * rr;
        quu[i] -= m * qr;
      }
    }
    float xx[16];
#pragma unroll
    for (int r = 15; r >= 0; --r) {
      float s = rhs[r];
#pragma unroll
      for (int c = r + 1; c < 16; ++c) s -= __shfl(quu[r], c) * xx[c];
      xx[r] = s * __builtin_amdgcn_rcpf(__shfl(quu[r], r));
    }
    // Kt^T -> LDS bf16 (each wave writes its own copy; identical values)
    if (lane < 32) {
      bf16x8 h0, l0, h1, l1;
#pragma unroll
      for (int u = 0; u < 8; ++u) {
        float kv = -xx[u];
        __bf16 hh = (__bf16)kv;
        h0[u] = hh; l0[u] = (__bf16)(kv - (float)hh);
        float kv2 = -xx[8 + u];
        __bf16 hh2 = (__bf16)kv2;
        h1[u] = hh2; l1[u] = (__bf16)(kv2 - (float)hh2);
      }
      *(bf16x8*)&sKTh[lane][0] = h0;
      *(bf16x8*)&sKTh[lane][8] = h1;
      *(bf16x8*)&sKTl[lane][0] = l0;
      *(bf16x8*)&sKTl[lane][8] = l1;
    }
    if (w == 0) {  // fp32 K/k to workspace (single wave, no duplicate traffic)
      if (lane < 32) {
        float4* dst = (float4*)(wsK + (((size_t)b * Td + t) * 32 + lane) * 16);
        float4 v0 = {-xx[0], -xx[1], -xx[2], -xx[3]};
        float4 v1 = {-xx[4], -xx[5], -xx[6], -xx[7]};
        float4 v2 = {-xx[8], -xx[9], -xx[10], -xx[11]};
        float4 v3 = {-xx[12], -xx[13], -xx[14], -xx[15]};
        dst[0] = v0; dst[1] = v1; dst[2] = v2; dst[3] = v3;
      } else if (lane == 32) {
        float4* dst = (float4*)(wskv + ((size_t)b * Td + t) * 16);
        float4 v0 = {-xx[0], -xx[1], -xx[2], -xx[3]};
        float4 v1 = {-xx[4], -xx[5], -xx[6], -xx[7]};
        float4 v2 = {-xx[8], -xx[9], -xx[10], -xx[11]};
        float4 v3 = {-xx[12], -xx[13], -xx[14], -xx[15]};
        dst[0] = v0; dst[1] = v1; dst[2] = v2; dst[3] = v3;
      }
    }

    // P4: Vn = Qxx + Qxu @ Kt (sKT written by own wave; sX covered by B2)
    if (w == 0) {
      bf16x8 aH = *(const bf16x8*)&sXh[fn][k0];
      bf16x8 aL = *(const bf16x8*)&sXl[fn][k0];
      bf16x8 bH = *(const bf16x8*)&sKTh[fn][k0];
      bf16x8 bL = *(const bf16x8*)&sKTl[fn][k0];
      accQ = MFMA16(aL, bH, accQ);
      accQ = MFMA16(aH, bL, accQ);
      accQ = MFMA16(aH, bH, accQ);
#pragma unroll
      for (int r = 0; r < 4; ++r) {
        float v = accQ[r];
        __bf16 h = (__bf16)v;
        sVh[4 * quad + r][fn] = h;
        sVl[4 * quad + r][fn] = (__bf16)(v - (float)h);
      }
    } else if (w == 1) {
      bf16x8 aH = *(const bf16x8*)&sXh[16 + fn][k0];
      bf16x8 aL = *(const bf16x8*)&sXl[16 + fn][k0];
      bf16x8 bH = *(const bf16x8*)&sKTh[16 + fn][k0];
      bf16x8 bL = *(const bf16x8*)&sKTl[16 + fn][k0];
      accQ = MFMA16(aL, bH, accQ);
      accQ = MFMA16(aH, bL, accQ);
      accQ = MFMA16(aH, bH, accQ);
#pragma unroll
      for (int r = 0; r < 4; ++r) {
        float v = accQ[r];
        __bf16 h = (__bf16)v;
        sVh[16 + 4 * quad + r][16 + fn] = h;
        sVl[16 + 4 * quad + r][16 + fn] = (__bf16)(v - (float)h);
      }
    } else if (w == 2) {
      bf16x8 aH = *(const bf16x8*)&sXh[fn][k0];
      bf16x8 aL = *(const bf16x8*)&sXl[fn][k0];
      bf16x8 bH = *(const bf16x8*)&sKTh[16 + fn][k0];
      bf16x8 bL = *(const bf16x8*)&sKTl[16 + fn][k0];
      accQ = MFMA16(aL, bH, accQ);
      accQ = MFMA16(aH, bL, accQ);
      accQ = MFMA16(aH, bH, accQ);
      bf16x4 th, tl;
#pragma unroll
      for (int r = 0; r < 4; ++r) {
        float v = accQ[r];
        __bf16 h = (__bf16)v;
        __bf16 l = (__bf16)(v - (float)h);
        sVh[4 * quad + r][16 + fn] = h;
        sVl[4 * quad + r][16 + fn] = l;
        th[r] = h; tl[r] = l;
      }
      *(bf16x4*)&sVh[16 + fn][4 * quad] = th;  // mirror (V symmetric)
      *(bf16x4*)&sVl[16 + fn][4 * quad] = tl;
    } else {  // vn = qx + Qxu @ kt  (kt = -xx on lane 32, broadcast by shfl)
      float acc = 0.f;
      bf16x8 xh0, xh1, xl0, xl1;
      if (lane < 32) {
        xh0 = *(const bf16x8*)&sXh[lane][0];
        xh1 = *(const bf16x8*)&sXh[lane][8];
        xl0 = *(const bf16x8*)&sXl[lane][0];
        xl1 = *(const bf16x8*)&sXl[lane][8];
        acc = sqt[lane];
      }
#pragma unroll
      for (int u = 0; u < 8; ++u) {
        float kt0 = -__shfl(xx[u], 32);
        float kt1 = -__shfl(xx[8 + u], 32);
        if (lane < 32) {
          acc += ((float)xh0[u] + (float)xl0[u]) * kt0;
          acc += ((float)xh1[u] + (float)xl1[u]) * kt1;
        }
      }
      if (lane < 32) svv[lane] = acc;
    }
    __syncthreads();  // B3 (end of step)
  }

  // ---------------- forward rollout: 2 barriers/step ----------------
  // sQ currently holds Q[b,0]. Pre-stage K/k/p for t=0.
  {
    const size_t kb = ((size_t)b * Td) << 9;
    if (tid < 128) {
      float4 v = ((const float4*)(wsK + kb))[tid];
      *(float4*)&sKT2[0][tid >> 2][(tid & 3) * 4] = v;
    } else if (tid < 144) {
      skt2[0][tid - 128] = wskv[((size_t)b * Td) * 16 + (tid - 128)];
    } else if (tid < 192) {
      spf[0][tid - 144] = pg[((size_t)b * Td) * 48 + (tid - 144)];
    }
  }
  __syncthreads();

  float costAcc = 0.f;
  float4 qpf0, qpf1, qpf2, kpf;
  float kkpf, ppf2;
  for (int t = 0; t < Td; ++t) {
    const int cur = t & 1, nxt = cur ^ 1;
    // commit Q[t] (prefetched last iteration; sQ last read before B2(t-1))
    if (t > 0) {
      float4* dst = (float4*)sQ;
      dst[tid] = qpf0;
      dst[tid + 256] = qpf1;
      if (tid < 64) dst[tid + 512] = qpf2;
    }
    // issue prefetches for t+1
    if (t < Td - 1) {
      const float4* src = (const float4*)(Qg + ((size_t)b * Td + t + 1) * 2304);
      qpf0 = src[tid];
      qpf1 = src[tid + 256];
      if (tid < 64) qpf2 = src[tid + 512];
      if (tid >= 128) {
        kpf = ((const float4*)(wsK + (((size_t)b * Td + t + 1) << 9)))[tid - 128];
      } else if (w == 1 && lane >= 32 && lane < 48) {
        kkpf = wskv[((size_t)b * Td + t + 1) * 16 + (lane - 32)];
        ppf2 = pg[((size_t)b * Td + t + 1) * 48 + 32 + (lane - 32)];
      } else if (w == 0 && lane >= 48) {
        ppf2 = pg[((size_t)b * Td + t + 1) * 48 + (lane - 48)];
      } else if (w == 1 && lane >= 48) {
        ppf2 = pg[((size_t)b * Td + t + 1) * 48 + 16 + (lane - 48)];
      }
    }
    // PhaseA: u (w3), x emit (w0), cost reduce of prev sred (w2)
    if (w == 3) {
      if (lane < 16) {
        float acc = skt2[cur][lane];
#pragma unroll
        for (int j = 0; j < 32; ++j)
          acc += sKT2[cur][j][lane] * (ssx[j] - scx[t][j]);
        sxu[32 + lane] = acc;
        out[UOFF + ((size_t)b * Td + t) * 16 + lane] = acc;
      }
    } else if (w == 0) {
      if (lane < 32) {
        float xv = ssx[lane];
        sxu[lane] = xv;
        out[XOFF + ((size_t)b * Td + t) * 32 + lane] = xv;
      }
    } else if (w == 2) {
      float rv = (t > 0 && lane < 48) ? sred[lane] : 0.f;
      rv += __shfl_down(rv, 32);
      rv += __shfl_down(rv, 16);
      rv += __shfl_down(rv, 8);
      rv += __shfl_down(rv, 4);
      rv += __shfl_down(rv, 2);
      rv += __shfl_down(rv, 1);
      if (lane == 0) costAcc += rv;
    }
    __syncthreads();  // B1
    // PhaseB: y/red (w0<48), xn->ssx (w1<32), K/k/p commits (rest)
    if (w == 0 && lane < 48) {
      float y = 0.f;
#pragma unroll
      for (int j = 0; j < 48; ++j) y += sQ[j * 48 + lane] * sxu[j];
      sred[lane] = sxu[lane] * (0.5f * y + spf[cur][lane]);
    } else if (w == 1 && lane < 32) {
      float acc = 0.f;
#pragma unroll
      for (int j = 0; j < 48; ++j) acc += sFf[lane][j] * sxu[j];
      ssx[lane] = acc;
    }
    if (t < Td - 1) {
      if (tid >= 128) {
        int i2 = tid - 128;
        *(float4*)&sKT2[nxt][i2 >> 2][(i2 & 3) * 4] = kpf;
      } else if (w == 1 && lane >= 32 && lane < 48) {
        skt2[nxt][lane - 32] = kkpf;
        spf[nxt][32 + (lane - 32)] = ppf2;
      } else if (w == 0 && lane >= 48) {
        spf[nxt][lane - 48] = ppf2;
      } else if (w == 1 && lane >= 48) {
        spf[nxt][16 + (lane - 48)] = ppf2;
      }
    }
    __syncthreads();  // B2
  }
  // final cost: reduce sred of t=63
  if (w == 2) {
    float rv = (lane < 48) ? sred[lane] : 0.f;
    rv += __shfl_down(rv, 32);
    rv += __shfl_down(rv, 16);
    rv += __shfl_down(rv, 8);
    rv += __shfl_down(rv, 4);
    rv += __shfl_down(rv, 2);
    rv += __shfl_down(rv, 1);
    if (lane == 0) out[COFF + b] = costAcc + rv;
  }
}

extern "C" void kernel_launch(void* const* d_in, const int* in_sizes, int n_in,
                              void* d_out, int out_size, void* d_ws, size_t ws_size,
                              hipStream_t stream) {
  const float* x_init = (const float*)d_in[0];
  const float* Qg = (const float*)d_in[1];
  const float* pg = (const float*)d_in[2];
  const float* Ag = (const float*)d_in[3];
  const float* Bg = (const float*)d_in[4];
  float* out = (float*)d_out;
  float* wsK = (float*)d_ws;
  float* wskv = wsK + (size_t)NBd * Td * NSd * NCd;
  lqr_kernel<<<NBd, 256, 0, stream>>>(x_init, Qg, pg, Ag, Bg, out, wsK, wskv);
}

// Round 3
// 762.187 us; speedup vs baseline: 1.3635x; 1.2343x over previous
//
#include <hip/hip_runtime.h>

// LQR2: NS=32, NC=16, T=64, NB=512, NSC=48
// out: x[512][64][32] | u[512][64][16] | cost[512]
// ws:  K^T fp32 [512][64][32][16]  then k fp32 [512][64][16]  (~69 MB)
//
// R3: solve via v_readlane (compile-time lane idx -> SGPR broadcast) instead
// of __shfl/ds_bpermute chains (~270 serial LDS-pipe ops/step was the R2
// bottleneck). LDS diet to 52.5 KB -> 3 blocks/CU (launch_bounds 256,3).

#define NSd 32
#define NCd 16
#define Td 64
#define NBd 512
#define NSCd 48

typedef __bf16 bf16x8 __attribute__((ext_vector_type(8)));
typedef __bf16 bf16x4 __attribute__((ext_vector_type(4)));
typedef float f32x4 __attribute__((ext_vector_type(4)));

#define MFMA16(a, b, c) __builtin_amdgcn_mfma_f32_16x16x32_bf16(a, b, c, 0, 0, 0)

#define XOFF ((size_t)0)
#define UOFF ((size_t)NBd * Td * NSd)
#define COFF (UOFF + (size_t)NBd * Td * NCd)

__device__ __forceinline__ float rdl(float v, int l) {
  return __uint_as_float(__builtin_amdgcn_readlane(__float_as_uint(v), l));
}

__global__ __launch_bounds__(256, 3) void lqr_kernel(
    const float* __restrict__ x_init, const float* __restrict__ Qg,
    const float* __restrict__ pg, const float* __restrict__ Ag,
    const float* __restrict__ Bg, float* __restrict__ out,
    float* __restrict__ wsK, float* __restrict__ wskv) {
  const int b = blockIdx.x;
  const int tid = threadIdx.x;
  const int w = tid >> 6;
  const int lane = tid & 63;
  const int fn = lane & 15;
  const int quad = lane >> 4;
  const int k0 = quad * 8;

  // ---------------- LDS (~52.5 KB -> 3 blocks/CU) ----------------
  __shared__ __attribute__((aligned(16))) float sQ[2304];
  __shared__ float scx[Td][NSd];
  __shared__ float sFf[NSd][NSCd];
  __shared__ __attribute__((aligned(16))) __bf16 sFTh[NSCd][32], sFTl[NSCd][32];
  __shared__ __attribute__((aligned(16))) __bf16 sVh[NSd][32], sVl[NSd][32];
  __shared__ __attribute__((aligned(16))) __bf16 sWTh[NSCd][32], sWTl[NSCd][32];
  __shared__ __attribute__((aligned(16))) __bf16 sXh[NSd][32], sXl[NSd][32];
  __shared__ __attribute__((aligned(16))) __bf16 sKTh[NSd][32], sKTl[NSd][32];
  __shared__ float sQuu[16][17];
  __shared__ float sqt[NSCd];
  __shared__ float svv[NSd];
  __shared__ __attribute__((aligned(16))) float sKT2[NSd][NCd];  // single-buffered
  __shared__ float skt2[NCd], spf[2][NSCd];
  __shared__ float sxu[NSCd], sred[NSCd], ssx[NSd];

  // ---------------- setup ----------------
  for (int idx = tid; idx < 1536; idx += 256) {
    int i = idx / 48, j = idx - i * 48;
    sFf[i][j] = (j < 32) ? Ag[i * 32 + j] : Bg[i * 16 + (j - 32)];
  }
  for (int idx = tid; idx < 1536; idx += 256) {
    int a = idx >> 5, k = idx & 31;
    float f = (a < 32) ? Ag[k * 32 + a] : Bg[k * 16 + (a - 32)];
    __bf16 h = (__bf16)f;
    sFTh[a][k] = h;
    sFTl[a][k] = (__bf16)(f - (float)h);
  }
  for (int idx = tid; idx < 1024; idx += 256) {
    int r = idx >> 5, c = idx & 31;
    __bf16 z = (__bf16)0.f;
    sVh[r][c] = z; sVl[r][c] = z;
    sXh[r][c] = z; sXl[r][c] = z;
    sKTh[r][c] = z; sKTl[r][c] = z;
  }
  if (tid < 32) {
    float xi = x_init[b * 32 + tid];
    scx[0][tid] = xi;
    ssx[tid] = xi;
    svv[tid] = 0.f;
  }
  {  // stage Q[b,63]
    const float4* src = (const float4*)(Qg + ((size_t)b * Td + 63) * 2304);
    float4* dst = (float4*)sQ;
    dst[tid] = src[tid];
    dst[tid + 256] = src[tid + 256];
    if (tid < 64) dst[tid + 512] = src[tid + 512];
  }
  float ppf = 0.f;  // backward p[t] prefetch (w3 lanes<48)
  if (w == 3 && lane < 48) ppf = pg[((size_t)b * Td + 63) * 48 + lane];
  __syncthreads();

  // cx rollout, wave-0 synchronous
  if (w == 0) {
    for (int t2 = 0; t2 < Td - 1; ++t2) {
      if (lane < 32) {
        float acc = 0.f;
#pragma unroll
        for (int j = 0; j < 32; j += 4) {
          float4 a4 = *(const float4*)&sFf[lane][j];
          acc += a4.x * scx[t2][j] + a4.y * scx[t2][j + 1] +
                 a4.z * scx[t2][j + 2] + a4.w * scx[t2][j + 3];
        }
        scx[t2 + 1][lane] = acc;
      }
    }
  }
  __syncthreads();

  // ---------------- backward Riccati: 3 barriers/step ----------------
  for (int t = Td - 1; t >= 0; --t) {
    float4 pf0, pf1, pf2;
    float ppfn;
    if (t > 0) {  // prefetch Q[t-1], p[t-1]
      const float4* src = (const float4*)(Qg + ((size_t)b * Td + (t - 1)) * 2304);
      pf0 = src[tid];
      pf1 = src[tid + 256];
      if (tid < 64) pf2 = src[tid + 512];
      if (w == 3 && lane < 48) ppfn = pg[((size_t)b * Td + t - 1) * 48 + lane];
    }
    // P0: w0-2: WT = F^T V (V symmetric). w3: qt vector.
    if (w < 3) {
      const int I = w;
      bf16x8 aH = *(const bf16x8*)&sFTh[16 * I + fn][k0];
      bf16x8 aL = *(const bf16x8*)&sFTl[16 * I + fn][k0];
#pragma unroll
      for (int J = 0; J < 2; ++J) {
        bf16x8 bH = *(const bf16x8*)&sVh[16 * J + fn][k0];
        bf16x8 bL = *(const bf16x8*)&sVl[16 * J + fn][k0];
        f32x4 acc = {0.f, 0.f, 0.f, 0.f};
        acc = MFMA16(aL, bH, acc);
        acc = MFMA16(aH, bL, acc);
        acc = MFMA16(aH, bH, acc);
#pragma unroll
        for (int r = 0; r < 4; ++r) {
          float v = acc[r];
          __bf16 h = (__bf16)v;
          sWTh[16 * I + 4 * quad + r][16 * J + fn] = h;
          sWTl[16 * I + 4 * quad + r][16 * J + fn] = (__bf16)(v - (float)h);
        }
      }
    } else if (lane < 48) {
      float acc = ppf;
#pragma unroll
      for (int k = 0; k < 32; ++k) acc += sQ[k * 48 + lane] * scx[t][k];
#pragma unroll
      for (int k = 0; k < 32; ++k) acc += svv[k] * sFf[k][lane];
      sqt[lane] = acc;
    }
    if (t > 0 && w == 3) ppf = ppfn;
    __syncthreads();  // B1

    // P1: Qt = Q + WT@F, 6 unique tiles over 4 waves.
    f32x4 accQ = {0.f, 0.f, 0.f, 0.f};
    if (w < 2) {
      const int I = w;
      bf16x8 aH = *(const bf16x8*)&sWTh[16 * I + fn][k0];
      bf16x8 aL = *(const bf16x8*)&sWTl[16 * I + fn][k0];
      {
        bf16x8 bH = *(const bf16x8*)&sFTh[16 * I + fn][k0];
        bf16x8 bL = *(const bf16x8*)&sFTl[16 * I + fn][k0];
#pragma unroll
        for (int r = 0; r < 4; ++r)
          accQ[r] = sQ[(16 * I + 4 * quad + r) * 48 + 16 * I + fn];
        accQ = MFMA16(aL, bH, accQ);
        accQ = MFMA16(aH, bL, accQ);
        accQ = MFMA16(aH, bH, accQ);
      }
      {
        bf16x8 bH = *(const bf16x8*)&sFTh[32 + fn][k0];
        bf16x8 bL = *(const bf16x8*)&sFTl[32 + fn][k0];
        f32x4 acc;
#pragma unroll
        for (int r = 0; r < 4; ++r)
          acc[r] = sQ[(16 * I + 4 * quad + r) * 48 + 32 + fn];
        acc = MFMA16(aL, bH, acc);
        acc = MFMA16(aH, bL, acc);
        acc = MFMA16(aH, bH, acc);
#pragma unroll
        for (int r = 0; r < 4; ++r) {
          float v = acc[r];
          __bf16 h = (__bf16)v;
          sXh[16 * I + 4 * quad + r][fn] = h;
          sXl[16 * I + 4 * quad + r][fn] = (__bf16)(v - (float)h);
        }
      }
    } else if (w == 2) {
      bf16x8 aH = *(const bf16x8*)&sWTh[fn][k0];
      bf16x8 aL = *(const bf16x8*)&sWTl[fn][k0];
      bf16x8 bH = *(const bf16x8*)&sFTh[16 + fn][k0];
      bf16x8 bL = *(const bf16x8*)&sFTl[16 + fn][k0];
#pragma unroll
      for (int r = 0; r < 4; ++r)
        accQ[r] = sQ[(4 * quad + r) * 48 + 16 + fn];
      accQ = MFMA16(aL, bH, accQ);
      accQ = MFMA16(aH, bL, accQ);
      accQ = MFMA16(aH, bH, accQ);
    } else {
      bf16x8 aH = *(const bf16x8*)&sWTh[32 + fn][k0];
      bf16x8 aL = *(const bf16x8*)&sWTl[32 + fn][k0];
      bf16x8 bH = *(const bf16x8*)&sFTh[32 + fn][k0];
      bf16x8 bL = *(const bf16x8*)&sFTl[32 + fn][k0];
      f32x4 acc;
#pragma unroll
      for (int r = 0; r < 4; ++r)
        acc[r] = sQ[(32 + 4 * quad + r) * 48 + 32 + fn];
      acc = MFMA16(aL, bH, acc);
      acc = MFMA16(aH, bL, acc);
      acc = MFMA16(aH, bH, acc);
#pragma unroll
      for (int r = 0; r < 4; ++r) sQuu[4 * quad + r][fn] = acc[r];
    }
    __syncthreads();  // B2

    // commit Q prefetch
    if (t > 0) {
      float4* dst = (float4*)sQ;
      dst[tid] = pf0;
      dst[tid + 256] = pf1;
      if (tid < 64) dst[tid + 512] = pf2;
    }

    // P2: wave-synchronous solve Quu * X = [Qux | qu], readlane broadcasts.
    float rhs[16];
    if (lane < 32) {
      bf16x8 xh0 = *(const bf16x8*)&sXh[lane][0];
      bf16x8 xh1 = *(const bf16x8*)&sXh[lane][8];
      bf16x8 xl0 = *(const bf16x8*)&sXl[lane][0];
      bf16x8 xl1 = *(const bf16x8*)&sXl[lane][8];
#pragma unroll
      for (int i = 0; i < 8; ++i) {
        rhs[i] = (float)xh0[i] + (float)xl0[i];
        rhs[8 + i] = (float)xh1[i] + (float)xl1[i];
      }
    } else {
#pragma unroll
      for (int i = 0; i < 16; ++i) rhs[i] = sqt[32 + i];
    }
    float quu[16];
#pragma unroll
    for (int i = 0; i < 16; ++i) quu[i] = sQuu[i][fn];
#pragma unroll
    for (int r = 0; r < 15; ++r) {
      float inv = __builtin_amdgcn_rcpf(rdl(quu[r], r));
#pragma unroll
      for (int i = r + 1; i < 16; ++i) {
        float m = rdl(quu[i], r) * inv;
        rhs[i] -= m * rhs[r];
        quu[i] -= m * quu[r];
      }
    }
    float xx[16];
#pragma unroll
    for (int r = 15; r >= 0; --r) {
      float s = rhs[r];
#pragma unroll
      for (int c = r + 1; c < 16; ++c) s -= rdl(quu[r], c) * xx[c];
      xx[r] = s * __builtin_amdgcn_rcpf(rdl(quu[r], r));
    }
    // Kt^T -> LDS bf16 (each wave its own copy; identical values)
    if (lane < 32) {
      bf16x8 h0, l0, h1, l1;
#pragma unroll
      for (int u = 0; u < 8; ++u) {
        float kv = -xx[u];
        __bf16 hh = (__bf16)kv;
        h0[u] = hh; l0[u] = (__bf16)(kv - (float)hh);
        float kv2 = -xx[8 + u];
        __bf16 hh2 = (__bf16)kv2;
        h1[u] = hh2; l1[u] = (__bf16)(kv2 - (float)hh2);
      }
      *(bf16x8*)&sKTh[lane][0] = h0;
      *(bf16x8*)&sKTh[lane][8] = h1;
      *(bf16x8*)&sKTl[lane][0] = l0;
      *(bf16x8*)&sKTl[lane][8] = l1;
    }
    if (w == 0) {  // fp32 K/k to workspace
      if (lane < 32) {
        float4* dst = (float4*)(wsK + (((size_t)b * Td + t) * 32 + lane) * 16);
        float4 v0 = {-xx[0], -xx[1], -xx[2], -xx[3]};
        float4 v1 = {-xx[4], -xx[5], -xx[6], -xx[7]};
        float4 v2 = {-xx[8], -xx[9], -xx[10], -xx[11]};
        float4 v3 = {-xx[12], -xx[13], -xx[14], -xx[15]};
        dst[0] = v0; dst[1] = v1; dst[2] = v2; dst[3] = v3;
      } else if (lane == 32) {
        float4* dst = (float4*)(wskv + ((size_t)b * Td + t) * 16);
        float4 v0 = {-xx[0], -xx[1], -xx[2], -xx[3]};
        float4 v1 = {-xx[4], -xx[5], -xx[6], -xx[7]};
        float4 v2 = {-xx[8], -xx[9], -xx[10], -xx[11]};
        float4 v3 = {-xx[12], -xx[13], -xx[14], -xx[15]};
        dst[0] = v0; dst[1] = v1; dst[2] = v2; dst[3] = v3;
      }
    }

    // P4: Vn = Qxx + Qxu @ Kt; w3: vn
    if (w == 0) {
      bf16x8 aH = *(const bf16x8*)&sXh[fn][k0];
      bf16x8 aL = *(const bf16x8*)&sXl[fn][k0];
      bf16x8 bH = *(const bf16x8*)&sKTh[fn][k0];
      bf16x8 bL = *(const bf16x8*)&sKTl[fn][k0];
      accQ = MFMA16(aL, bH, accQ);
      accQ = MFMA16(aH, bL, accQ);
      accQ = MFMA16(aH, bH, accQ);
#pragma unroll
      for (int r = 0; r < 4; ++r) {
        float v = accQ[r];
        __bf16 h = (__bf16)v;
        sVh[4 * quad + r][fn] = h;
        sVl[4 * quad + r][fn] = (__bf16)(v - (float)h);
      }
    } else if (w == 1) {
      bf16x8 aH = *(const bf16x8*)&sXh[16 + fn][k0];
      bf16x8 aL = *(const bf16x8*)&sXl[16 + fn][k0];
      bf16x8 bH = *(const bf16x8*)&sKTh[16 + fn][k0];
      bf16x8 bL = *(const bf16x8*)&sKTl[16 + fn][k0];
      accQ = MFMA16(aL, bH, accQ);
      accQ = MFMA16(aH, bL, accQ);
      accQ = MFMA16(aH, bH, accQ);
#pragma unroll
      for (int r = 0; r < 4; ++r) {
        float v = accQ[r];
        __bf16 h = (__bf16)v;
        sVh[16 + 4 * quad + r][16 + fn] = h;
        sVl[16 + 4 * quad + r][16 + fn] = (__bf16)(v - (float)h);
      }
    } else if (w == 2) {
      bf16x8 aH = *(const bf16x8*)&sXh[fn][k0];
      bf16x8 aL = *(const bf16x8*)&sXl[fn][k0];
      bf16x8 bH = *(const bf16x8*)&sKTh[16 + fn][k0];
      bf16x8 bL = *(const bf16x8*)&sKTl[16 + fn][k0];
      accQ = MFMA16(aL, bH, accQ);
      accQ = MFMA16(aH, bL, accQ);
      accQ = MFMA16(aH, bH, accQ);
      bf16x4 th, tl;
#pragma unroll
      for (int r = 0; r < 4; ++r) {
        float v = accQ[r];
        __bf16 h = (__bf16)v;
        __bf16 l = (__bf16)(v - (float)h);
        sVh[4 * quad + r][16 + fn] = h;
        sVl[4 * quad + r][16 + fn] = l;
        th[r] = h; tl[r] = l;
      }
      *(bf16x4*)&sVh[16 + fn][4 * quad] = th;  // mirror (V symmetric)
      *(bf16x4*)&sVl[16 + fn][4 * quad] = tl;
    } else {  // vn = qx + Qxu @ kt  (kt = -xx on lane 32)
      float acc = 0.f;
      bf16x8 xh0, xh1, xl0, xl1;
      if (lane < 32) {
        xh0 = *(const bf16x8*)&sXh[lane][0];
        xh1 = *(const bf16x8*)&sXh[lane][8];
        xl0 = *(const bf16x8*)&sXl[lane][0];
        xl1 = *(const bf16x8*)&sXl[lane][8];
        acc = sqt[lane];
      }
#pragma unroll
      for (int u = 0; u < 8; ++u) {
        float kt0 = -rdl(xx[u], 32);
        float kt1 = -rdl(xx[8 + u], 32);
        if (lane < 32) {
          acc += ((float)xh0[u] + (float)xl0[u]) * kt0;
          acc += ((float)xh1[u] + (float)xl1[u]) * kt1;
        }
      }
      if (lane < 32) svv[lane] = acc;
    }
    __syncthreads();  // B3
  }

  // ---------------- forward rollout: 2 barriers/step ----------------
  {
    const size_t kb = ((size_t)b * Td) << 9;
    if (tid < 128) {
      float4 v = ((const float4*)(wsK + kb))[tid];
      *(float4*)&sKT2[tid >> 2][(tid & 3) * 4] = v;
    } else if (tid < 144) {
      skt2[tid - 128] = wskv[((size_t)b * Td) * 16 + (tid - 128)];
    } else if (tid < 192) {
      spf[0][tid - 144] = pg[((size_t)b * Td) * 48 + (tid - 144)];
    }
  }
  __syncthreads();

  float costAcc = 0.f;
  float4 qpf0, qpf1, qpf2, kpf;
  float kkpf, ppf2;
  for (int t = 0; t < Td; ++t) {
    const int cur = t & 1, nxt = cur ^ 1;
    if (t > 0) {  // commit Q[t]
      float4* dst = (float4*)sQ;
      dst[tid] = qpf0;
      dst[tid + 256] = qpf1;
      if (tid < 64) dst[tid + 512] = qpf2;
    }
    if (t < Td - 1) {  // prefetch t+1
      const float4* src = (const float4*)(Qg + ((size_t)b * Td + t + 1) * 2304);
      qpf0 = src[tid];
      qpf1 = src[tid + 256];
      if (tid < 64) qpf2 = src[tid + 512];
      if (tid >= 128) {
        kpf = ((const float4*)(wsK + (((size_t)b * Td + t + 1) << 9)))[tid - 128];
      } else if (w == 1 && lane >= 32 && lane < 48) {
        kkpf = wskv[((size_t)b * Td + t + 1) * 16 + (lane - 32)];
        ppf2 = pg[((size_t)b * Td + t + 1) * 48 + 32 + (lane - 32)];
      } else if (w == 0 && lane >= 48) {
        ppf2 = pg[((size_t)b * Td + t + 1) * 48 + (lane - 48)];
      } else if (w == 1 && lane >= 48) {
        ppf2 = pg[((size_t)b * Td + t + 1) * 48 + 16 + (lane - 48)];
      }
    }
    // PhaseA: u (w3), x emit (w0), cost reduce of prev sred (w2)
    if (w == 3) {
      if (lane < 16) {
        float acc = skt2[lane];
#pragma unroll
        for (int j = 0; j < 32; ++j)
          acc += sKT2[j][lane] * (ssx[j] - scx[t][j]);
        sxu[32 + lane] = acc;
        out[UOFF + ((size_t)b * Td + t) * 16 + lane] = acc;
      }
    } else if (w == 0) {
      if (lane < 32) {
        float xv = ssx[lane];
        sxu[lane] = xv;
        out[XOFF + ((size_t)b * Td + t) * 32 + lane] = xv;
      }
    } else if (w == 2) {
      float rv = (t > 0 && lane < 48) ? sred[lane] : 0.f;
      rv += __shfl_down(rv, 32);
      rv += __shfl_down(rv, 16);
      rv += __shfl_down(rv, 8);
      rv += __shfl_down(rv, 4);
      rv += __shfl_down(rv, 2);
      rv += __shfl_down(rv, 1);
      if (lane == 0) costAcc += rv;
    }
    __syncthreads();  // B1
    // PhaseB: y/red (w0<48), xn->ssx (w1<32), K/k/p commits (rest)
    if (w == 0 && lane < 48) {
      float y = 0.f;
#pragma unroll
      for (int j = 0; j < 48; ++j) y += sQ[j * 48 + lane] * sxu[j];
      sred[lane] = sxu[lane] * (0.5f * y + spf[cur][lane]);
    } else if (w == 1 && lane < 32) {
      float acc = 0.f;
#pragma unroll
      for (int j = 0; j < 48; ++j) acc += sFf[lane][j] * sxu[j];
      ssx[lane] = acc;
    }
    if (t < Td - 1) {
      if (tid >= 128) {
        int i2 = tid - 128;
        *(float4*)&sKT2[i2 >> 2][(i2 & 3) * 4] = kpf;
      } else if (w == 1 && lane >= 32 && lane < 48) {
        skt2[lane - 32] = kkpf;
        spf[nxt][32 + (lane - 32)] = ppf2;
      } else if (w == 0 && lane >= 48) {
        spf[nxt][lane - 48] = ppf2;
      } else if (w == 1 && lane >= 48) {
        spf[nxt][16 + (lane - 48)] = ppf2;
      }
    }
    __syncthreads();  // B2
  }
  // final cost: reduce sred of t=63
  if (w == 2) {
    float rv = (lane < 48) ? sred[lane] : 0.f;
    rv += __shfl_down(rv, 32);
    rv += __shfl_down(rv, 16);
    rv += __shfl_down(rv, 8);
    rv += __shfl_down(rv, 4);
    rv += __shfl_down(rv, 2);
    rv += __shfl_down(rv, 1);
    if (lane == 0) out[COFF + b] = costAcc + rv;
  }
}

extern "C" void kernel_launch(void* const* d_in, const int* in_sizes, int n_in,
                              void* d_out, int out_size, void* d_ws, size_t ws_size,
                              hipStream_t stream) {
  const float* x_init = (const float*)d_in[0];
  const float* Qg = (const float*)d_in[1];
  const float* pg = (const float*)d_in[2];
  const float* Ag = (const float*)d_in[3];
  const float* Bg = (const float*)d_in[4];
  float* out = (float*)d_out;
  float* wsK = (float*)d_ws;
  float* wskv = wsK + (size_t)NBd * Td * NSd * NCd;
  lqr_kernel<<<NBd, 256, 0, stream>>>(x_init, Qg, pg, Ag, Bg, out, wsK, wskv);
}

// Round 4
// 667.722 us; speedup vs baseline: 1.5564x; 1.1415x over previous
//
#include <hip/hip_runtime.h>

// LQR2: NS=32, NC=16, T=64, NB=512, NSC=48
// out: x[512][64][32] | u[512][64][16] | cost[512]
// ws:  K^T fp32 [512][64][32][16]  then k fp32 [512][64][16]
//
// R4: (a) cost computed analytically during backward (cost = sum_t const_t +
// sum_t 0.5*qu.kt, valid since dx0=0) -> forward Q re-read eliminated;
// (b) solve on ONE wave (alternating 3/2) instead of 4x redundant, +B2.5;
// (c) forward = barrier-free wave-synchronous recurrence on w0 only.

#define NSd 32
#define NCd 16
#define Td 64
#define NBd 512
#define NSCd 48

typedef __bf16 bf16x8 __attribute__((ext_vector_type(8)));
typedef __bf16 bf16x4 __attribute__((ext_vector_type(4)));
typedef float f32x4 __attribute__((ext_vector_type(4)));

#define MFMA16(a, b, c) __builtin_amdgcn_mfma_f32_16x16x32_bf16(a, b, c, 0, 0, 0)

#define XOFF ((size_t)0)
#define UOFF ((size_t)NBd * Td * NSd)
#define COFF (UOFF + (size_t)NBd * Td * NCd)

__device__ __forceinline__ float rdl(float v, int l) {
  return __uint_as_float(__builtin_amdgcn_readlane(__float_as_uint(v), l));
}

union LdsU {
  struct {  // backward phase
    __bf16 FTh[48][32], FTl[48][32];
    __bf16 Vh[32][32], Vl[32][32];
    __bf16 WTh[48][32], WTl[48][32];
    __bf16 Xh[32][32], Xl[32][32];
    __bf16 KTh[32][32], KTl[32][32];
    float Quu[16][17];
    float qt[48];
    float vv[32];
    float kt[16];
  } bw;
  struct {  // forward phase (overlays dead backward fragments)
    float K2T[2][16 * 36];  // row stride 36 (bank-conflict pad, 16B aligned)
    float kv2[2][16];
    float d[32];
    float xs[32];
    float uu[16];
  } fw;
};

__global__ __launch_bounds__(256, 2) void lqr_kernel(
    const float* __restrict__ x_init, const float* __restrict__ Qg,
    const float* __restrict__ pg, const float* __restrict__ Ag,
    const float* __restrict__ Bg, float* __restrict__ out,
    float* __restrict__ wsK, float* __restrict__ wskv) {
  const int b = blockIdx.x;
  const int tid = threadIdx.x;
  const int w = tid >> 6;
  const int lane = tid & 63;
  const int fn = lane & 15;
  const int quad = lane >> 4;
  const int k0 = quad * 8;

  __shared__ __attribute__((aligned(16))) float sQ[2304];
  __shared__ float scx[Td][NSd];
  __shared__ float sFf[NSd][NSCd];
  __shared__ __attribute__((aligned(16))) LdsU U;
  __shared__ float scostp[4];

  // ---------------- setup ----------------
  for (int idx = tid; idx < 1536; idx += 256) {
    int i = idx / 48, j = idx - i * 48;
    sFf[i][j] = (j < 32) ? Ag[i * 32 + j] : Bg[i * 16 + (j - 32)];
  }
  for (int idx = tid; idx < 1536; idx += 256) {
    int a = idx >> 5, k = idx & 31;
    float f = (a < 32) ? Ag[k * 32 + a] : Bg[k * 16 + (a - 32)];
    __bf16 h = (__bf16)f;
    U.bw.FTh[a][k] = h;
    U.bw.FTl[a][k] = (__bf16)(f - (float)h);
  }
  for (int idx = tid; idx < 1024; idx += 256) {
    int r = idx >> 5, c = idx & 31;
    __bf16 z = (__bf16)0.f;
    U.bw.Vh[r][c] = z; U.bw.Vl[r][c] = z;
    U.bw.Xh[r][c] = z; U.bw.Xl[r][c] = z;
    U.bw.KTh[r][c] = z; U.bw.KTl[r][c] = z;
  }
  if (tid < 32) {
    scx[0][tid] = x_init[b * 32 + tid];
    U.bw.vv[tid] = 0.f;
  }
  {  // stage Q[b,63]
    const float4* src = (const float4*)(Qg + ((size_t)b * Td + 63) * 2304);
    float4* dst = (float4*)sQ;
    dst[tid] = src[tid];
    dst[tid + 256] = src[tid + 256];
    if (tid < 64) dst[tid + 512] = src[tid + 512];
  }
  float ppf = 0.f;
  if (w == 3 && lane < 48) ppf = pg[((size_t)b * Td + 63) * 48 + lane];
  __syncthreads();

  // cx rollout, wave-0 synchronous
  if (w == 0) {
    for (int t2 = 0; t2 < Td - 1; ++t2) {
      if (lane < 32) {
        float acc = 0.f;
#pragma unroll
        for (int j = 0; j < 32; j += 4) {
          float4 a4 = *(const float4*)&sFf[lane][j];
          acc += a4.x * scx[t2][j] + a4.y * scx[t2][j + 1] +
                 a4.z * scx[t2][j + 2] + a4.w * scx[t2][j + 3];
        }
        scx[t2 + 1][lane] = acc;
      }
    }
  }
  __syncthreads();

  float cAcc = 0.f;  // w3 lanes<32: sum_t 0.5*cx'(p + 0.5*Q*cx) terms
  float dAcc = 0.f;  // solver wave lane32: sum_t 0.5*qu.kt

  // ---------------- backward Riccati: 4 barriers/step ----------------
  for (int t = Td - 1; t >= 0; --t) {
    const int sw = 3 - (t & 1);  // solver wave alternates 3,2
    float4 pf0, pf1, pf2;
    float ppfn;
    if (t > 0) {
      const float4* src = (const float4*)(Qg + ((size_t)b * Td + (t - 1)) * 2304);
      pf0 = src[tid];
      pf1 = src[tid + 256];
      if (tid < 64) pf2 = src[tid + 512];
      if (w == 3 && lane < 48) ppfn = pg[((size_t)b * Td + t - 1) * 48 + lane];
    }
    // P0: w0-2: WT = F^T V. w3: qt vector + cost const term.
    if (w < 3) {
      const int I = w;
      bf16x8 aH = *(const bf16x8*)&U.bw.FTh[16 * I + fn][k0];
      bf16x8 aL = *(const bf16x8*)&U.bw.FTl[16 * I + fn][k0];
#pragma unroll
      for (int J = 0; J < 2; ++J) {
        bf16x8 bH = *(const bf16x8*)&U.bw.Vh[16 * J + fn][k0];
        bf16x8 bL = *(const bf16x8*)&U.bw.Vl[16 * J + fn][k0];
        f32x4 acc = {0.f, 0.f, 0.f, 0.f};
        acc = MFMA16(aL, bH, acc);
        acc = MFMA16(aH, bL, acc);
        acc = MFMA16(aH, bH, acc);
#pragma unroll
        for (int r = 0; r < 4; ++r) {
          float v = acc[r];
          __bf16 h = (__bf16)v;
          U.bw.WTh[16 * I + 4 * quad + r][16 * J + fn] = h;
          U.bw.WTl[16 * I + 4 * quad + r][16 * J + fn] = (__bf16)(v - (float)h);
        }
      }
    } else if (lane < 48) {
      float acc1 = ppf;  // p + Q*cxu
#pragma unroll
      for (int k = 0; k < 32; ++k) acc1 += sQ[k * 48 + lane] * scx[t][k];
      if (lane < 32) cAcc += 0.5f * scx[t][lane] * (acc1 + ppf);
      float acc = acc1;
#pragma unroll
      for (int k = 0; k < 32; ++k) acc += U.bw.vv[k] * sFf[k][lane];
      U.bw.qt[lane] = acc;
    }
    if (t > 0 && w == 3) ppf = ppfn;
    __syncthreads();  // B1

    // P1: Qt = Q + WT@F, 6 unique tiles over 4 waves.
    f32x4 accQ = {0.f, 0.f, 0.f, 0.f};
    if (w < 2) {
      const int I = w;
      bf16x8 aH = *(const bf16x8*)&U.bw.WTh[16 * I + fn][k0];
      bf16x8 aL = *(const bf16x8*)&U.bw.WTl[16 * I + fn][k0];
      {
        bf16x8 bH = *(const bf16x8*)&U.bw.FTh[16 * I + fn][k0];
        bf16x8 bL = *(const bf16x8*)&U.bw.FTl[16 * I + fn][k0];
#pragma unroll
        for (int r = 0; r < 4; ++r)
          accQ[r] = sQ[(16 * I + 4 * quad + r) * 48 + 16 * I + fn];
        accQ = MFMA16(aL, bH, accQ);
        accQ = MFMA16(aH, bL, accQ);
        accQ = MFMA16(aH, bH, accQ);
      }
      {
        bf16x8 bH = *(const bf16x8*)&U.bw.FTh[32 + fn][k0];
        bf16x8 bL = *(const bf16x8*)&U.bw.FTl[32 + fn][k0];
        f32x4 acc;
#pragma unroll
        for (int r = 0; r < 4; ++r)
          acc[r] = sQ[(16 * I + 4 * quad + r) * 48 + 32 + fn];
        acc = MFMA16(aL, bH, acc);
        acc = MFMA16(aH, bL, acc);
        acc = MFMA16(aH, bH, acc);
#pragma unroll
        for (int r = 0; r < 4; ++r) {
          float v = acc[r];
          __bf16 h = (__bf16)v;
          U.bw.Xh[16 * I + 4 * quad + r][fn] = h;
          U.bw.Xl[16 * I + 4 * quad + r][fn] = (__bf16)(v - (float)h);
        }
      }
    } else if (w == 2) {
      bf16x8 aH = *(const bf16x8*)&U.bw.WTh[fn][k0];
      bf16x8 aL = *(const bf16x8*)&U.bw.WTl[fn][k0];
      bf16x8 bH = *(const bf16x8*)&U.bw.FTh[16 + fn][k0];
      bf16x8 bL = *(const bf16x8*)&U.bw.FTl[16 + fn][k0];
#pragma unroll
      for (int r = 0; r < 4; ++r)
        accQ[r] = sQ[(4 * quad + r) * 48 + 16 + fn];
      accQ = MFMA16(aL, bH, accQ);
      accQ = MFMA16(aH, bL, accQ);
      accQ = MFMA16(aH, bH, accQ);
    } else {
      bf16x8 aH = *(const bf16x8*)&U.bw.WTh[32 + fn][k0];
      bf16x8 aL = *(const bf16x8*)&U.bw.WTl[32 + fn][k0];
      bf16x8 bH = *(const bf16x8*)&U.bw.FTh[32 + fn][k0];
      bf16x8 bL = *(const bf16x8*)&U.bw.FTl[32 + fn][k0];
      f32x4 acc;
#pragma unroll
      for (int r = 0; r < 4; ++r)
        acc[r] = sQ[(32 + 4 * quad + r) * 48 + 32 + fn];
      acc = MFMA16(aL, bH, acc);
      acc = MFMA16(aH, bL, acc);
      acc = MFMA16(aH, bH, acc);
#pragma unroll
      for (int r = 0; r < 4; ++r) U.bw.Quu[4 * quad + r][fn] = acc[r];
    }
    __syncthreads();  // B2

    // commit Q prefetch (all waves; all sQ reads done)
    if (t > 0) {
      float4* dst = (float4*)sQ;
      dst[tid] = pf0;
      dst[tid + 256] = pf1;
      if (tid < 64) dst[tid + 512] = pf2;
    }

    // P2: SOLVER WAVE ONLY: Quu * X = [Qux | qu] via readlane broadcasts.
    if (w == sw) {
      float rhs[16];
      if (lane < 32) {
        bf16x8 xh0 = *(const bf16x8*)&U.bw.Xh[lane][0];
        bf16x8 xh1 = *(const bf16x8*)&U.bw.Xh[lane][8];
        bf16x8 xl0 = *(const bf16x8*)&U.bw.Xl[lane][0];
        bf16x8 xl1 = *(const bf16x8*)&U.bw.Xl[lane][8];
#pragma unroll
        for (int i = 0; i < 8; ++i) {
          rhs[i] = (float)xh0[i] + (float)xl0[i];
          rhs[8 + i] = (float)xh1[i] + (float)xl1[i];
        }
      } else {
#pragma unroll
        for (int i = 0; i < 16; ++i) rhs[i] = U.bw.qt[32 + i];
      }
      float quu[16];
#pragma unroll
      for (int i = 0; i < 16; ++i) quu[i] = U.bw.Quu[i][fn];
#pragma unroll
      for (int r = 0; r < 15; ++r) {
        float inv = __builtin_amdgcn_rcpf(rdl(quu[r], r));
#pragma unroll
        for (int i = r + 1; i < 16; ++i) {
          float m = rdl(quu[i], r) * inv;
          rhs[i] -= m * rhs[r];
          quu[i] -= m * quu[r];
        }
      }
      float xx[16];
#pragma unroll
      for (int r = 15; r >= 0; --r) {
        float s = rhs[r];
#pragma unroll
        for (int c = r + 1; c < 16; ++c) s -= rdl(quu[r], c) * xx[c];
        xx[r] = s * __builtin_amdgcn_rcpf(rdl(quu[r], r));
      }
      if (lane < 32) {  // Kt^T bf16 to LDS + fp32 K to ws
        bf16x8 h0, l0, h1, l1;
#pragma unroll
        for (int u = 0; u < 8; ++u) {
          float kv = -xx[u];
          __bf16 hh = (__bf16)kv;
          h0[u] = hh; l0[u] = (__bf16)(kv - (float)hh);
          float kv2 = -xx[8 + u];
          __bf16 hh2 = (__bf16)kv2;
          h1[u] = hh2; l1[u] = (__bf16)(kv2 - (float)hh2);
        }
        *(bf16x8*)&U.bw.KTh[lane][0] = h0;
        *(bf16x8*)&U.bw.KTh[lane][8] = h1;
        *(bf16x8*)&U.bw.KTl[lane][0] = l0;
        *(bf16x8*)&U.bw.KTl[lane][8] = l1;
        float4* dst = (float4*)(wsK + (((size_t)b * Td + t) * 32 + lane) * 16);
        float4 v0 = {-xx[0], -xx[1], -xx[2], -xx[3]};
        float4 v1 = {-xx[4], -xx[5], -xx[6], -xx[7]};
        float4 v2 = {-xx[8], -xx[9], -xx[10], -xx[11]};
        float4 v3 = {-xx[12], -xx[13], -xx[14], -xx[15]};
        dst[0] = v0; dst[1] = v1; dst[2] = v2; dst[3] = v3;
      } else if (lane == 32) {  // kt to LDS + ws; cost Δc term
#pragma unroll
        for (int u = 0; u < 16; ++u) U.bw.kt[u] = -xx[u];
        float4* dst = (float4*)(wskv + ((size_t)b * Td + t) * 16);
        float4 v0 = {-xx[0], -xx[1], -xx[2], -xx[3]};
        float4 v1 = {-xx[4], -xx[5], -xx[6], -xx[7]};
        float4 v2 = {-xx[8], -xx[9], -xx[10], -xx[11]};
        float4 v3 = {-xx[12], -xx[13], -xx[14], -xx[15]};
        dst[0] = v0; dst[1] = v1; dst[2] = v2; dst[3] = v3;
        float s = 0.f;
#pragma unroll
        for (int i = 0; i < 16; ++i) s += U.bw.qt[32 + i] * xx[i];
        dAcc -= 0.5f * s;
      }
      if (sw == 3) {  // vn on w3 using local xx (pre-barrier)
        float acc = 0.f;
        bf16x8 xh0, xh1, xl0, xl1;
        if (lane < 32) {
          xh0 = *(const bf16x8*)&U.bw.Xh[lane][0];
          xh1 = *(const bf16x8*)&U.bw.Xh[lane][8];
          xl0 = *(const bf16x8*)&U.bw.Xl[lane][0];
          xl1 = *(const bf16x8*)&U.bw.Xl[lane][8];
          acc = U.bw.qt[lane];
        }
#pragma unroll
        for (int u = 0; u < 8; ++u) {
          float kt0 = -rdl(xx[u], 32);
          float kt1 = -rdl(xx[8 + u], 32);
          if (lane < 32) {
            acc += ((float)xh0[u] + (float)xl0[u]) * kt0;
            acc += ((float)xh1[u] + (float)xl1[u]) * kt1;
          }
        }
        if (lane < 32) U.bw.vv[lane] = acc;
      }
    }
    __syncthreads();  // B2.5: K ready

    // P4: Vn = Qxx + Qxu @ Kt on w0-2; vn on w3 when solver was w2
    if (w == 0) {
      bf16x8 aH = *(const bf16x8*)&U.bw.Xh[fn][k0];
      bf16x8 aL = *(const bf16x8*)&U.bw.Xl[fn][k0];
      bf16x8 bH = *(const bf16x8*)&U.bw.KTh[fn][k0];
      bf16x8 bL = *(const bf16x8*)&U.bw.KTl[fn][k0];
      accQ = MFMA16(aL, bH, accQ);
      accQ = MFMA16(aH, bL, accQ);
      accQ = MFMA16(aH, bH, accQ);
#pragma unroll
      for (int r = 0; r < 4; ++r) {
        float v = accQ[r];
        __bf16 h = (__bf16)v;
        U.bw.Vh[4 * quad + r][fn] = h;
        U.bw.Vl[4 * quad + r][fn] = (__bf16)(v - (float)h);
      }
    } else if (w == 1) {
      bf16x8 aH = *(const bf16x8*)&U.bw.Xh[16 + fn][k0];
      bf16x8 aL = *(const bf16x8*)&U.bw.Xl[16 + fn][k0];
      bf16x8 bH = *(const bf16x8*)&U.bw.KTh[16 + fn][k0];
      bf16x8 bL = *(const bf16x8*)&U.bw.KTl[16 + fn][k0];
      accQ = MFMA16(aL, bH, accQ);
      accQ = MFMA16(aH, bL, accQ);
      accQ = MFMA16(aH, bH, accQ);
#pragma unroll
      for (int r = 0; r < 4; ++r) {
        float v = accQ[r];
        __bf16 h = (__bf16)v;
        U.bw.Vh[16 + 4 * quad + r][16 + fn] = h;
        U.bw.Vl[16 + 4 * quad + r][16 + fn] = (__bf16)(v - (float)h);
      }
    } else if (w == 2) {
      bf16x8 aH = *(const bf16x8*)&U.bw.Xh[fn][k0];
      bf16x8 aL = *(const bf16x8*)&U.bw.Xl[fn][k0];
      bf16x8 bH = *(const bf16x8*)&U.bw.KTh[16 + fn][k0];
      bf16x8 bL = *(const bf16x8*)&U.bw.KTl[16 + fn][k0];
      accQ = MFMA16(aL, bH, accQ);
      accQ = MFMA16(aH, bL, accQ);
      accQ = MFMA16(aH, bH, accQ);
      bf16x4 th, tl;
#pragma unroll
      for (int r = 0; r < 4; ++r) {
        float v = accQ[r];
        __bf16 h = (__bf16)v;
        __bf16 l = (__bf16)(v - (float)h);
        U.bw.Vh[4 * quad + r][16 + fn] = h;
        U.bw.Vl[4 * quad + r][16 + fn] = l;
        th[r] = h; tl[r] = l;
      }
      *(bf16x4*)&U.bw.Vh[16 + fn][4 * quad] = th;  // mirror (V symmetric)
      *(bf16x4*)&U.bw.Vl[16 + fn][4 * quad] = tl;
    } else if (sw == 2) {  // w3: vn using LDS kt
      if (lane < 32) {
        bf16x8 xh0 = *(const bf16x8*)&U.bw.Xh[lane][0];
        bf16x8 xh1 = *(const bf16x8*)&U.bw.Xh[lane][8];
        bf16x8 xl0 = *(const bf16x8*)&U.bw.Xl[lane][0];
        bf16x8 xl1 = *(const bf16x8*)&U.bw.Xl[lane][8];
        float acc = U.bw.qt[lane];
#pragma unroll
        for (int u = 0; u < 8; ++u) {
          acc += ((float)xh0[u] + (float)xl0[u]) * U.bw.kt[u];
          acc += ((float)xh1[u] + (float)xl1[u]) * U.bw.kt[8 + u];
        }
        U.bw.vv[lane] = acc;
      }
    }
    __syncthreads();  // B3 (end of step)
  }

  // ---------------- cost partials, then union flips to forward ----------------
  if (w == 3) {
    float rv = (lane < 32) ? cAcc : 0.f;
    rv += __shfl_down(rv, 32);
    rv += __shfl_down(rv, 16);
    rv += __shfl_down(rv, 8);
    rv += __shfl_down(rv, 4);
    rv += __shfl_down(rv, 2);
    rv += __shfl_down(rv, 1);
    if (lane == 0) scostp[0] = rv;
  }
  if (lane == 32 && w >= 2) scostp[w - 1] = dAcc;  // w2->[1], w3->[2]
  __syncthreads();  // backward reads done; union may be overwritten

  // ---------------- forward: wave-0 synchronous, barrier-free ----------------
  if (w == 0) {
    {  // preload K_0, k_0 into buf 0 (transposed, stride 36)
      const float4* src = (const float4*)(wsK + ((size_t)b * Td) * 512);
      float4 ka = src[lane * 2], kb = src[lane * 2 + 1];
      int jj = lane >> 1, ib = (lane & 1) * 8;
      float* kt2 = U.fw.K2T[0];
      kt2[(ib + 0) * 36 + jj] = ka.x; kt2[(ib + 1) * 36 + jj] = ka.y;
      kt2[(ib + 2) * 36 + jj] = ka.z; kt2[(ib + 3) * 36 + jj] = ka.w;
      kt2[(ib + 4) * 36 + jj] = kb.x; kt2[(ib + 5) * 36 + jj] = kb.y;
      kt2[(ib + 6) * 36 + jj] = kb.z; kt2[(ib + 7) * 36 + jj] = kb.w;
      if (lane < 16) U.fw.kv2[0][lane] = wskv[(size_t)b * Td * 16 + lane];
    }
    float xr = (lane < 32) ? scx[0][lane] : 0.f;
    for (int t = 0; t < Td; ++t) {
      const int cur = t & 1, nxt = cur ^ 1;
      float4 pa, pb;
      float pk;
      if (t < Td - 1) {  // prefetch K_{t+1}
        const float4* src = (const float4*)(wsK + ((size_t)b * Td + t + 1) * 512);
        pa = src[lane * 2];
        pb = src[lane * 2 + 1];
        if (lane < 16) pk = wskv[((size_t)b * Td + t + 1) * 16 + lane];
      }
      if (lane < 32) {  // d = x - cx; stash x; emit x
        U.fw.d[lane] = xr - scx[t][lane];
        U.fw.xs[lane] = xr;
        out[XOFF + ((size_t)b * Td + t) * 32 + lane] = xr;
      }
      if (lane < 16) {  // u = k + K d; emit u
        float uv = U.fw.kv2[cur][lane];
        const float* kr = &U.fw.K2T[cur][lane * 36];
#pragma unroll
        for (int j4 = 0; j4 < 8; ++j4) {
          float4 kk = *(const float4*)&kr[j4 * 4];
          float4 dd = *(const float4*)&U.fw.d[j4 * 4];
          uv += kk.x * dd.x + kk.y * dd.y + kk.z * dd.z + kk.w * dd.w;
        }
        U.fw.uu[lane] = uv;
        out[UOFF + ((size_t)b * Td + t) * 16 + lane] = uv;
      }
      if (lane < 32) {  // x' = A x + B u
        float acc = 0.f;
#pragma unroll
        for (int j4 = 0; j4 < 8; ++j4) {
          float4 ff = *(const float4*)&sFf[lane][j4 * 4];
          float4 xv = *(const float4*)&U.fw.xs[j4 * 4];
          acc += ff.x * xv.x + ff.y * xv.y + ff.z * xv.z + ff.w * xv.w;
        }
#pragma unroll
        for (int j4 = 0; j4 < 4; ++j4) {
          float4 ff = *(const float4*)&sFf[lane][32 + j4 * 4];
          float4 uv = *(const float4*)&U.fw.uu[j4 * 4];
          acc += ff.x * uv.x + ff.y * uv.y + ff.z * uv.z + ff.w * uv.w;
        }
        xr = acc;
      }
      if (t < Td - 1) {  // commit K_{t+1}
        int jj = lane >> 1, ib = (lane & 1) * 8;
        float* kt2 = U.fw.K2T[nxt];
        kt2[(ib + 0) * 36 + jj] = pa.x; kt2[(ib + 1) * 36 + jj] = pa.y;
        kt2[(ib + 2) * 36 + jj] = pa.z; kt2[(ib + 3) * 36 + jj] = pa.w;
        kt2[(ib + 4) * 36 + jj] = pb.x; kt2[(ib + 5) * 36 + jj] = pb.y;
        kt2[(ib + 6) * 36 + jj] = pb.z; kt2[(ib + 7) * 36 + jj] = pb.w;
        if (lane < 16) U.fw.kv2[nxt][lane] = pk;
      }
    }
    if (lane == 0) out[COFF + b] = scostp[0] + scostp[1] + scostp[2];
  }
}

extern "C" void kernel_launch(void* const* d_in, const int* in_sizes, int n_in,
                              void* d_out, int out_size, void* d_ws, size_t ws_size,
                              hipStream_t stream) {
  const float* x_init = (const float*)d_in[0];
  const float* Qg = (const float*)d_in[1];
  const float* pg = (const float*)d_in[2];
  const float* Ag = (const float*)d_in[3];
  const float* Bg = (const float*)d_in[4];
  float* out = (float*)d_out;
  float* wsK = (float*)d_ws;
  float* wskv = wsK + (size_t)NBd * Td * NSd * NCd;
  lqr_kernel<<<NBd, 256, 0, stream>>>(x_init, Qg, pg, Ag, Bg, out, wsK, wskv);
}